// Round 12
// baseline (218.682 us; speedup 1.0000x reference)
//
#include <hip/hip_runtime.h>

// SelfAttention: B=4, L=4096, H=256, fp32 in/out.
// Round 21: r20 minus the permlane32_swap experiment (NaN post-mortem: a
// wrong +-32 lane-max drops the lane's own value from mn -> exp2(s-mn)
// overflows f16 P -> inf*V -> NaN. permlane32_swap's gfx950 half-exchange
// semantics are unverified here; DO NOT re-add without an isolated probe).
// tmax +-32 step reverted to the proven __shfl_xor(tmax, 32).
// KEPT from r20: (a) l-sum as per-lane partials merged once at epilogue
// (exact: linear recurrence, quad-uniform alpha; hardware-proven in r16) -
// DS ops/tile 8 -> 4; (c) qkv dual-scratch epilogues (Tf dedicated + Tf2
// aliasing the dead WlS; barriers 4->2 (K) and 4->1 (V); address-identical
// to the r19-passing layout).
// Carried: Q/K 3-product split-bf16 (r15: 2-product flips near-tie argmax),
// V-phase 2-product, 2 row-sets/wave qkv (grid 128x4, one residency round),
// swapped-operand QK, per-lane softmax, in-lane P cvt via Vf bijection,
// 1 barrier/tile counted DMA, 2 q-sets/wave, split-K=4 grid 512, 4-way
// merge, (256,2) never-cap, trailing sched_barrier(0) (r16 spill lesson).

typedef __bf16 bf16x8 __attribute__((ext_vector_type(8)));
typedef _Float16 f16x8 __attribute__((ext_vector_type(8)));
typedef _Float16 f16x4 __attribute__((ext_vector_type(4)));
typedef float floatx4 __attribute__((ext_vector_type(4)));

#define MFMA16B(a, b, c) __builtin_amdgcn_mfma_f32_16x16x32_bf16(a, b, c, 0, 0, 0)
#define MFMA16F(a, b, c) __builtin_amdgcn_mfma_f32_16x16x32_f16(a, b, c, 0, 0, 0)
#define GLOAD_LDS16(g, l)                                                  \
  __builtin_amdgcn_global_load_lds(                                        \
      (const __attribute__((address_space(1))) void *)(g),                 \
      (__attribute__((address_space(3))) void *)(l), 16, 0, 0)

#define HID 256
#define LSEQ 4096
#define NB 4
#define NTOK (NB * LSEQ)             // 16384
#define PLANE ((size_t)NTOK * HID)   // 4,194,304 elements
#define NSPLIT 4                     // split-K over key range
#define QSCALE 0.09016844005556021f  // log2(e)/16 ; softmax uses exp2

// Layouts:
//  Wht/Wlt [3][n][h] row-major hi/lo bf16 weights (transposed).
//  Qf [tok][h] row-major fp16 (pre-scaled by QSCALE).
//  Kf (32-key tiles, T = tok>>5, 512 tiles): [T][nt(2)][kc(8)][lane(64)][j(8)]
//    fp16, tile stride 8192 el (16 KB).
//    element = K[key = T*32 + nt*16 + (lane&15)][h = kc*32 + (lane>>4)*8 + j]
//  Vf (32-key tiles): [T][dt(16)][lane][j] fp16, tile stride 8192 el.
//    element = V[key = T*32 + 4*(lane>>4) + (j&3) + 16*(j>>2)][d = dt*16 + (lane&15)]
//    (key<->k-slot bijection matches the swapped-QK per-lane key set).

__device__ __forceinline__ void split_bf16(float v, __bf16 &h, __bf16 &l) {
  h = (__bf16)v;
  l = (__bf16)(v - (float)h);
}

// ---------------------------------------------------------------------------
// Kernel 1: transpose + hi/lo-split weights -> Wht/Wlt [3][n][h] row-major.
// ---------------------------------------------------------------------------
__global__ __launch_bounds__(256) void wsplit(const float *__restrict__ Wq,
                                              const float *__restrict__ Wk,
                                              const float *__restrict__ Wv,
                                              __bf16 *__restrict__ Wht,
                                              __bf16 *__restrict__ Wlt) {
  __shared__ float tile[32][256];
  const int wsel = blockIdx.x;
  const int hb = blockIdx.y;
  const float *W = (wsel == 0) ? Wq : (wsel == 1) ? Wk : Wv;
  __bf16 *oh = Wht + wsel * HID * HID;
  __bf16 *ol = Wlt + wsel * HID * HID;
  const int t = threadIdx.x;
  #pragma unroll
  for (int p = 0; p < 8; ++p) {
    int r = p * 4 + (t >> 6);
    int c = (t & 63) * 4;
    *(floatx4 *)&tile[r][c] = *(const floatx4 *)&W[(hb * 32 + r) * HID + c];
  }
  __syncthreads();
  #pragma unroll
  for (int q = 0; q < 4; ++q) {
    int n = q * 64 + (t >> 2);
    int hs = (t & 3) * 8;
    bf16x8 hh, ll;
    #pragma unroll
    for (int i = 0; i < 8; ++i) {
      float v = tile[hs + i][n];
      __bf16 h, l;
      split_bf16(v, h, l);
      hh[i] = h; ll[i] = l;
    }
    *(bf16x8 *)&oh[n * HID + hb * 32 + hs] = hh;
    *(bf16x8 *)&ol[n * HID + hb * 32 + hs] = ll;
  }
}

// ---------------------------------------------------------------------------
// Kernel 2: QKV projection, 2 row-sets/wave (128-row m-tiles, grid (128,4) =
// 512 blocks = one residency round). Q/K: 3-product split-bf16; V: 2-product.
// Every W ds_read feeds 2 MFMAs. W temps load at phase top (short live range).
// K/V epilogues use dual scratch (Tf dedicated + Tf2 aliasing the dead WlS):
// both halves written, barriers 4->2 (K) and 4->1 (V), halves overlapped.
// ---------------------------------------------------------------------------
__global__ __launch_bounds__(256, 2) void qkv_proj(const float *__restrict__ X,
                                                   const __bf16 *__restrict__ Wht,
                                                   const __bf16 *__restrict__ Wlt,
                                                   _Float16 *__restrict__ Qf,
                                                   _Float16 *__restrict__ Kf,
                                                   _Float16 *__restrict__ Vf) {
  __shared__ __bf16 WhS[64 * 256];
  __shared__ __bf16 WlS[64 * 256];
  __shared__ _Float16 Tf[64 * 72];   // dedicated transpose scratch (half 0)

  const int mtile = blockIdx.x;      // 128-row m-tile
  const int col0 = blockIdx.y * 64;
  const int tid = threadIdx.x;
  const int w4 = tid >> 6;
  const int lane = tid & 63;
  const int quad = lane >> 4;
  const int ln = lane & 15;
  const int arow0 = mtile * 128 + w4 * 16 + ln;
  const int arow1 = arow0 + 64;

  bf16x8 ah0[8], al0[8], ah1[8], al1[8];
  #pragma unroll
  for (int kc = 0; kc < 8; ++kc) {
    {
      const float *xp = X + (size_t)arow0 * HID + kc * 32 + quad * 8;
      floatx4 x0 = *(const floatx4 *)xp;
      floatx4 x1 = *(const floatx4 *)(xp + 4);
      #pragma unroll
      for (int j = 0; j < 4; ++j) {
        __bf16 h, l;
        split_bf16(x0[j], h, l); ah0[kc][j] = h; al0[kc][j] = l;
        split_bf16(x1[j], h, l); ah0[kc][4 + j] = h; al0[kc][4 + j] = l;
      }
    }
    {
      const float *xp = X + (size_t)arow1 * HID + kc * 32 + quad * 8;
      floatx4 x0 = *(const floatx4 *)xp;
      floatx4 x1 = *(const floatx4 *)(xp + 4);
      #pragma unroll
      for (int j = 0; j < 4; ++j) {
        __bf16 h, l;
        split_bf16(x0[j], h, l); ah1[kc][j] = h; al1[kc][j] = l;
        split_bf16(x1[j], h, l); ah1[kc][4 + j] = h; al1[kc][4 + j] = l;
      }
    }
  }

  const int srow = tid >> 2;
  const int sseg = tid & 3;

  for (int w = 0; w < 3; ++w) {
    // W(w) slab into temps; live range ends at the staging write below.
    bf16x8 th[8], tl[8];
    {
      const size_t wbase = (size_t)w * HID * HID + (size_t)(col0 + srow) * HID;
      #pragma unroll
      for (int j = 0; j < 8; ++j) {
        const int chunk = j * 4 + sseg;
        th[j] = *(const bf16x8 *)&Wht[wbase + chunk * 8];
        if (w < 2) tl[j] = *(const bf16x8 *)&Wlt[wbase + chunk * 8];
      }
    }
    __syncthreads();  // prev phase's LDS consumers (MFMA / Tf2 reads) done
    #pragma unroll
    for (int j = 0; j < 8; ++j) {
      const int chunk = j * 4 + sseg;
      const int dst = srow * 256 + ((chunk ^ (srow & 7)) << 3);
      *(bf16x8 *)&WhS[dst] = th[j];
      if (w < 2) *(bf16x8 *)&WlS[dst] = tl[j];  // V phase reads hi only
    }
    __syncthreads();

    floatx4 acc0[4] = {}, acc1[4] = {};
    #pragma unroll
    for (int kc = 0; kc < 8; ++kc) {
      #pragma unroll
      for (int nt = 0; nt < 4; ++nt) {
        const int a = (nt * 16 + ln) * 256 + (((kc * 4 + quad) ^ (ln & 7)) << 3);
        bf16x8 bh = *(const bf16x8 *)&WhS[a];
        acc0[nt] = MFMA16B(ah0[kc], bh, acc0[nt]);
        acc1[nt] = MFMA16B(ah1[kc], bh, acc1[nt]);
        if (w < 2) {
          bf16x8 bl = *(const bf16x8 *)&WlS[a];
          acc0[nt] = MFMA16B(ah0[kc], bl, acc0[nt]);
          acc1[nt] = MFMA16B(ah1[kc], bl, acc1[nt]);
        }
        acc0[nt] = MFMA16B(al0[kc], bh, acc0[nt]);
        acc1[nt] = MFMA16B(al1[kc], bh, acc1[nt]);
      }
    }

    // Epilogues. C/D layout: col = lane&15, row = quad*4 + reg.
    if (w == 0) {
      #pragma unroll
      for (int nt = 0; nt < 4; ++nt) {
        #pragma unroll
        for (int r = 0; r < 4; ++r) {
          const int orow = mtile * 128 + w4 * 16 + quad * 4 + r;
          const int ocol = col0 + nt * 16 + ln;
          Qf[(size_t)orow * HID + ocol] = (_Float16)(acc0[nt][r] * QSCALE);
          Qf[(size_t)(orow + 64) * HID + ocol] = (_Float16)(acc1[nt][r] * QSCALE);
        }
      }
    } else if (w == 1) {
      _Float16 *Tf2 = (_Float16 *)WlS;  // WlS dead after this phase's MFMAs
      // half 0 -> Tf (dedicated; no hazard, write immediately)
      #pragma unroll
      for (int nt = 0; nt < 4; ++nt)
        #pragma unroll
        for (int r = 0; r < 4; ++r) {
          const int tok_l = w4 * 16 + quad * 4 + r;
          const int h_l = nt * 16 + ln;
          Tf[tok_l * 72 + h_l] = (_Float16)acc0[nt][r];
        }
      __syncthreads();  // all waves' MFMA reads of WhS/WlS done; Tf visible
      // half 1 -> Tf2 (aliases WlS, now free); overlaps half-0 shuffle reads
      #pragma unroll
      for (int nt = 0; nt < 4; ++nt)
        #pragma unroll
        for (int r = 0; r < 4; ++r) {
          const int tok_l = w4 * 16 + quad * 4 + r;
          const int h_l = nt * 16 + ln;
          Tf2[tok_l * 72 + h_l] = (_Float16)acc1[nt][r];
        }
      #pragma unroll
      for (int i = 0; i < 2; ++i) {     // half 0: 512 chunks of 16B
        const int c = i * 256 + tid;
        const int lane_f = c & 63;
        const int ntf = (c >> 6) & 1;
        const int kcL = (c >> 7) & 1;
        const int t2 = (c >> 8) & 1;
        const int qf = lane_f >> 4;
        const int lnf = lane_f & 15;
        const int tok_l = t2 * 32 + ntf * 16 + lnf;
        f16x8 v = *(const f16x8 *)&Tf[tok_l * 72 + kcL * 32 + qf * 8];
        const int T = mtile * 4 + t2;
        const int kc2 = (col0 >> 5) + kcL;
        *(f16x8 *)&Kf[(size_t)T * 8192 + ((ntf * 8 + kc2) * 64 + lane_f) * 8] = v;
      }
      __syncthreads();  // Tf2 visible
      #pragma unroll
      for (int i = 0; i < 2; ++i) {     // half 1
        const int c = i * 256 + tid;
        const int lane_f = c & 63;
        const int ntf = (c >> 6) & 1;
        const int kcL = (c >> 7) & 1;
        const int t2 = (c >> 8) & 1;
        const int qf = lane_f >> 4;
        const int lnf = lane_f & 15;
        const int tok_l = t2 * 32 + ntf * 16 + lnf;
        f16x8 v = *(const f16x8 *)&Tf2[tok_l * 72 + kcL * 32 + qf * 8];
        const int T = mtile * 4 + 2 + t2;
        const int kc2 = (col0 >> 5) + kcL;
        *(f16x8 *)&Kf[(size_t)T * 8192 + ((ntf * 8 + kc2) * 64 + lane_f) * 8] = v;
      }
      // w==2's phase-top barrier covers Tf2 reads before any WhS restage.
    } else {
      _Float16 *Tf2 = (_Float16 *)WlS;  // WlS entirely unused in the V phase
      #pragma unroll
      for (int nt = 0; nt < 4; ++nt)
        #pragma unroll
        for (int r = 0; r < 4; ++r) {
          const int tok_l = w4 * 16 + quad * 4 + r;
          const int d_l = nt * 16 + ln;
          Tf[d_l * 72 + tok_l] = (_Float16)acc0[nt][r];
          Tf2[d_l * 72 + tok_l] = (_Float16)acc1[nt][r];
        }
      __syncthreads();
      #pragma unroll
      for (int i = 0; i < 2; ++i) {     // half 0
        const int c = i * 256 + tid;
        const int lane_f = c & 63;
        const int dtL = (c >> 6) & 3;
        const int t2 = (c >> 8) & 1;
        const int qf = lane_f >> 4;
        const int lnf = lane_f & 15;
        const int d_l = dtL * 16 + lnf;
        // Bijection: v[j] = V_local[key = t2*32 + 4*qf + (j&3) + 16*(j>>2)][d_l]
        f16x4 lo = *(const f16x4 *)&Tf[d_l * 72 + t2 * 32 + 4 * qf];
        f16x4 hi = *(const f16x4 *)&Tf[d_l * 72 + t2 * 32 + 16 + 4 * qf];
        f16x8 v;
        v[0] = lo[0]; v[1] = lo[1]; v[2] = lo[2]; v[3] = lo[3];
        v[4] = hi[0]; v[5] = hi[1]; v[6] = hi[2]; v[7] = hi[3];
        const int T = mtile * 4 + t2;
        const int dt = (col0 >> 4) + dtL;
        *(f16x8 *)&Vf[(size_t)(T * 16 + dt) * 512 + lane_f * 8] = v;
      }
      #pragma unroll
      for (int i = 0; i < 2; ++i) {     // half 1
        const int c = i * 256 + tid;
        const int lane_f = c & 63;
        const int dtL = (c >> 6) & 3;
        const int t2 = (c >> 8) & 1;
        const int qf = lane_f >> 4;
        const int lnf = lane_f & 15;
        const int d_l = dtL * 16 + lnf;
        f16x4 lo = *(const f16x4 *)&Tf2[d_l * 72 + t2 * 32 + 4 * qf];
        f16x4 hi = *(const f16x4 *)&Tf2[d_l * 72 + t2 * 32 + 16 + 4 * qf];
        f16x8 v;
        v[0] = lo[0]; v[1] = lo[1]; v[2] = lo[2]; v[3] = lo[3];
        v[4] = hi[0]; v[5] = hi[1]; v[6] = hi[2]; v[7] = hi[3];
        const int T = mtile * 4 + 2 + t2;
        const int dt = (col0 >> 4) + dtL;
        *(f16x8 *)&Vf[(size_t)(T * 16 + dt) * 512 + lane_f * 8] = v;
      }
    }
  }
}

// ---------------------------------------------------------------------------
// Kernel 3: flash attention, swapped-operand core, 2 q-sets/wave.
// r19 structure with l-sum as per-lane partials (merged once at epilogue);
// tmax reduce = shfl_xor(16) + shfl_xor(32) (both proven). DS ops/tile 4.
// grid = 512 (qt=bx>>2 over 128-token q-blocks, ks=bx&3), 256 thr,
// LDS 64 KB (K/V dbuf), 2 blocks/CU.
// ---------------------------------------------------------------------------
__global__ __launch_bounds__(256, 2) void attn(const _Float16 *__restrict__ Qf,
                                               const _Float16 *__restrict__ Kf,
                                               const _Float16 *__restrict__ Vf,
                                               _Float16 *__restrict__ Op,
                                               float *__restrict__ Mp,
                                               float *__restrict__ Lp) {
  __shared__ _Float16 KS[2][8192];
  __shared__ _Float16 VS[2][8192];

  const int bx = blockIdx.x;
  const int ks = bx & 3;
  const int qt = bx >> 2;            // 0..127: 128-token q-block
  const int b = qt >> 5;             // 32 q-blocks per batch
  const int qtl = qt & 31;
  const int tid = threadIdx.x;
  const int w4 = tid >> 6;
  const int lane = tid & 63;
  const int quad = lane >> 4;
  const int ln = lane & 15;
  const int T0 = b * 128 + ks * 32;  // 32 key-tiles (1024 keys) per block

  // This lane's two q tokens (q = lane&15 in the swapped layout).
  const int qtok0 = b * LSEQ + qtl * 128 + w4 * 16 + ln;
  const int qtok1 = qtok0 + 64;
  f16x8 q0[8], q1[8];
  #pragma unroll
  for (int kc = 0; kc < 8; ++kc) {
    q0[kc] = *(const f16x8 *)&Qf[(size_t)qtok0 * HID + kc * 32 + quad * 8];
    q1[kc] = *(const f16x8 *)&Qf[(size_t)qtok1 * HID + kc * 32 + quad * 8];
  }

  const _Float16 *kuni = Kf + (size_t)T0 * 8192;
  const _Float16 *vuni = Vf + (size_t)T0 * 8192;
  const int koff = tid * 8;
  const int voff = lane * 8;

  // Prologue: DMA tile 0 -> buffers 0.
  #pragma unroll
  for (int i = 0; i < 4; ++i)
    GLOAD_LDS16(kuni + i * 2048 + koff, &KS[0][i * 2048 + koff]);
  #pragma unroll
  for (int i = 0; i < 4; ++i)
    GLOAD_LDS16(vuni + i * 2048 + koff, &VS[0][i * 2048 + koff]);

  float m0 = -1e30f, m1 = -1e30f;
  float l0 = 0.f, l1 = 0.f;  // PER-LANE partials; merged across quads at end
  floatx4 o0[16] = {}, o1[16] = {};

  for (int t = 0; t < 32; ++t) {
    const int buf = t & 1;
    // Own tile-t DMA done (issued one full tile ago); queue empty otherwise.
    asm volatile("s_waitcnt vmcnt(0)" ::: "memory");
    __builtin_amdgcn_s_barrier();  // all waves' quarters in LDS; prev bufs free
    __builtin_amdgcn_sched_barrier(0);
    if (t < 31) {
      const _Float16 *ksrc = kuni + (size_t)(t + 1) * 8192 + koff;
      const _Float16 *vsrc = vuni + (size_t)(t + 1) * 8192 + koff;
      #pragma unroll
      for (int i = 0; i < 4; ++i)
        GLOAD_LDS16(ksrc + i * 2048, &KS[buf ^ 1][i * 2048 + koff]);
      #pragma unroll
      for (int i = 0; i < 4; ++i)
        GLOAD_LDS16(vsrc + i * 2048, &VS[buf ^ 1][i * 2048 + koff]);
    }
    const _Float16 *Kb = KS[buf];
    const _Float16 *Vb = VS[buf];

    // ---------- QK^T swapped: S^T = mfma(K, Q); each K-frag feeds 2 MFMAs --
    floatx4 s00, s01, s10, s11;  // s{qset}{nt}
    {
      floatx4 a00 = {}, b00 = {}, a01 = {}, b01 = {};
      floatx4 a10 = {}, b10 = {}, a11 = {}, b11 = {};
      __builtin_amdgcn_s_setprio(1);
      #pragma unroll
      for (int kc = 0; kc < 4; ++kc) {
        const f16x8 k0 = *(const f16x8 *)(Kb + kc * 512 + voff);
        const f16x8 k1 = *(const f16x8 *)(Kb + (4 + kc) * 512 + voff);
        const f16x8 k2 = *(const f16x8 *)(Kb + (8 + kc) * 512 + voff);
        const f16x8 k3 = *(const f16x8 *)(Kb + (12 + kc) * 512 + voff);
        a00 = MFMA16F(k0, q0[kc], a00);
        a10 = MFMA16F(k0, q1[kc], a10);
        b00 = MFMA16F(k1, q0[4 + kc], b00);
        b10 = MFMA16F(k1, q1[4 + kc], b10);
        a01 = MFMA16F(k2, q0[kc], a01);
        a11 = MFMA16F(k2, q1[kc], a11);
        b01 = MFMA16F(k3, q0[4 + kc], b01);
        b11 = MFMA16F(k3, q1[4 + kc], b11);
      }
      __builtin_amdgcn_s_setprio(0);
      s00 = a00 + b00; s01 = a01 + b01;
      s10 = a10 + b10; s11 = a11 + b11;
    }

    // ---------- per-lane softmax over 32 keys, q-set 0 (q = ln) ----------
    float al0, al1;
    {
      float tmax = fmaxf(fmaxf(fmaxf(s00[0], s00[1]), fmaxf(s00[2], s00[3])),
                         fmaxf(fmaxf(s01[0], s01[1]), fmaxf(s01[2], s01[3])));
      tmax = fmaxf(tmax, __shfl_xor(tmax, 16));
      tmax = fmaxf(tmax, __shfl_xor(tmax, 32));
      const float mn = fmaxf(m0, tmax);
      al0 = exp2f(m0 - mn);
      #pragma unroll
      for (int i = 0; i < 4; ++i) {
        s00[i] = exp2f(s00[i] - mn);
        s01[i] = exp2f(s01[i] - mn);
      }
      const float rs = ((s00[0] + s00[1]) + (s00[2] + s00[3])) +
                       ((s01[0] + s01[1]) + (s01[2] + s01[3]));
      l0 = l0 * al0 + rs;  // lane partial
      m0 = mn;
    }
    // ---------- q-set 1 ----------
    {
      float tmax = fmaxf(fmaxf(fmaxf(s10[0], s10[1]), fmaxf(s10[2], s10[3])),
                         fmaxf(fmaxf(s11[0], s11[1]), fmaxf(s11[2], s11[3])));
      tmax = fmaxf(tmax, __shfl_xor(tmax, 16));
      tmax = fmaxf(tmax, __shfl_xor(tmax, 32));
      const float mn = fmaxf(m1, tmax);
      al1 = exp2f(m1 - mn);
      #pragma unroll
      for (int i = 0; i < 4; ++i) {
        s10[i] = exp2f(s10[i] - mn);
        s11[i] = exp2f(s11[i] - mn);
      }
      const float rs = ((s10[0] + s10[1]) + (s10[2] + s10[3])) +
                       ((s11[0] + s11[1]) + (s11[2] + s11[3]));
      l1 = l1 * al1 + rs;
      m1 = mn;
    }

    // ---------- P fragments: pure in-lane cvt ----------
    f16x8 pf0, pf1;
    pf0[0] = (_Float16)s00[0]; pf0[1] = (_Float16)s00[1];
    pf0[2] = (_Float16)s00[2]; pf0[3] = (_Float16)s00[3];
    pf0[4] = (_Float16)s01[0]; pf0[5] = (_Float16)s01[1];
    pf0[6] = (_Float16)s01[2]; pf0[7] = (_Float16)s01[3];
    pf1[0] = (_Float16)s10[0]; pf1[1] = (_Float16)s10[1];
    pf1[2] = (_Float16)s10[2]; pf1[3] = (_Float16)s10[3];
    pf1[4] = (_Float16)s11[0]; pf1[5] = (_Float16)s11[1];
    pf1[6] = (_Float16)s11[2]; pf1[7] = (_Float16)s11[3];

    // ---------- O rescale (alpha-skip, per q-set) ----------
    if (__any(al0 < 1.0f)) {
      #pragma unroll
      for (int dt = 0; dt < 16; ++dt) {
        o0[dt][0] *= al0; o0[dt][1] *= al0; o0[dt][2] *= al0; o0[dt][3] *= al0;
      }
    }
    if (__any(al1 < 1.0f)) {
      #pragma unroll
      for (int dt = 0; dt < 16; ++dt) {
        o1[dt][0] *= al1; o1[dt][1] *= al1; o1[dt][2] *= al1; o1[dt][3] *= al1;
      }
    }

    // ---------- O^T += V^T P ; each V-frag feeds 2 MFMAs ----------
    __builtin_amdgcn_s_setprio(1);
    #pragma unroll
    for (int dt = 0; dt < 16; ++dt) {
      const f16x8 vf = *(const f16x8 *)(Vb + dt * 512 + voff);
      o0[dt] = MFMA16F(vf, pf0, o0[dt]);
      o1[dt] = MFMA16F(vf, pf1, o1[dt]);
    }
    __builtin_amdgcn_s_setprio(0);
    __builtin_amdgcn_sched_barrier(0);
  }

  // Epilogue: merge l partials across quads (once), then store.
  l0 += __shfl_xor(l0, 16);
  l0 += __shfl_xor(l0, 32);
  l1 += __shfl_xor(l1, 16);
  l1 += __shfl_xor(l1, 32);

  #pragma unroll
  for (int dt = 0; dt < 16; ++dt) {
    f16x4 v4;
    v4[0] = (_Float16)o0[dt][0]; v4[1] = (_Float16)o0[dt][1];
    v4[2] = (_Float16)o0[dt][2]; v4[3] = (_Float16)o0[dt][3];
    *(f16x4 *)&Op[(size_t)ks * PLANE + (size_t)qtok0 * HID + dt * 16 + quad * 4] = v4;
    f16x4 w4v;
    w4v[0] = (_Float16)o1[dt][0]; w4v[1] = (_Float16)o1[dt][1];
    w4v[2] = (_Float16)o1[dt][2]; w4v[3] = (_Float16)o1[dt][3];
    *(f16x4 *)&Op[(size_t)ks * PLANE + (size_t)qtok1 * HID + dt * 16 + quad * 4] = w4v;
  }
  if (quad == 0) {
    Mp[ks * NTOK + qtok0] = m0;
    Lp[ks * NTOK + qtok0] = l0;
    Mp[ks * NTOK + qtok1] = m1;
    Lp[ks * NTOK + qtok1] = l1;
  }
}

// ---------------------------------------------------------------------------
// Kernel 4: split-K merge, 4-way (fp16 partials).
// ---------------------------------------------------------------------------
__global__ __launch_bounds__(256) void merge(const _Float16 *__restrict__ Op,
                                             const float *__restrict__ Mp,
                                             const float *__restrict__ Lp,
                                             float *__restrict__ Out) {
  const int row = blockIdx.x * 4 + (threadIdx.x >> 6);
  const int c = (threadIdx.x & 63) * 4;
  float ms[NSPLIT], ls[NSPLIT];
  #pragma unroll
  for (int s = 0; s < NSPLIT; ++s) {
    ms[s] = Mp[s * NTOK + row];
    ls[s] = Lp[s * NTOK + row];
  }
  const float M = fmaxf(fmaxf(ms[0], ms[1]), fmaxf(ms[2], ms[3]));
  float e[NSPLIT], den = 0.f;
  #pragma unroll
  for (int s = 0; s < NSPLIT; ++s) {
    e[s] = exp2f(ms[s] - M);
    den += ls[s] * e[s];
  }
  const float inv = 1.0f / den;
  floatx4 out = {};
  #pragma unroll
  for (int s = 0; s < NSPLIT; ++s) {
    const f16x4 a = *(const f16x4 *)&Op[(size_t)s * PLANE + (size_t)row * HID + c];
    const float w = e[s] * inv;
    #pragma unroll
    for (int i = 0; i < 4; ++i) out[i] += w * (float)a[i];
  }
  *(floatx4 *)&Out[(size_t)row * HID + c] = out;
}

// ---------------------------------------------------------------------------
extern "C" void kernel_launch(void *const *d_in, const int *in_sizes, int n_in,
                              void *d_out, int out_size, void *d_ws, size_t ws_size,
                              hipStream_t stream) {
  const float *X = (const float *)d_in[0];
  const float *Wq = (const float *)d_in[1];
  const float *Wk = (const float *)d_in[2];
  const float *Wv = (const float *)d_in[3];
  // d_in[4] = lengths (unused by reference)

  // Workspace (2-byte elements). ~60 MB total.
  _Float16 *ws = (_Float16 *)d_ws;
  _Float16 *Qf = ws;                          // [16384][256] row-major fp16
  _Float16 *Kf = Qf + PLANE;                  // 32-key frag-linear fp16
  _Float16 *Vf = Kf + PLANE;                  // 32-key frag-linear fp16
  __bf16 *Wht = (__bf16 *)(Vf + PLANE);       // [3][256][256] bf16 hi
  __bf16 *Wlt = Wht + 3 * HID * HID;          // bf16 lo
  _Float16 *Op = (_Float16 *)(Wlt + 3 * HID * HID);  // [4][16384][256] fp16
  float *Mp = (float *)(Op + NSPLIT * PLANE); // [4][16384]
  float *Lp = Mp + NSPLIT * NTOK;             // [4][16384]

  wsplit<<<dim3(3, 8), 256, 0, stream>>>(Wq, Wk, Wv, Wht, Wlt);
  qkv_proj<<<dim3(128, 4), 256, 0, stream>>>(X, Wht, Wlt, Qf, Kf, Vf);
  attn<<<NTOK / 128 * NSPLIT, 256, 0, stream>>>(Qf, Kf, Vf, Op, Mp, Lp);
  merge<<<NTOK / 4, 256, 0, stream>>>(Op, Mp, Lp, (float *)d_out);
}

// Round 13
// 201.830 us; speedup vs baseline: 1.0835x; 1.0835x over previous
//
#include <hip/hip_runtime.h>

// SelfAttention: B=4, L=4096, H=256, fp32 in/out.
// Round 22: recombine best-measured kernels. r21 post-mortem: the l-partial
// softmax transformation is the attn spill trigger (common factor across
// r16/r17/r21 spills; r14/r18/r19 without it are clean) - shortening the
// softmax dep chain lets the scheduler widen s/P live ranges past the
// ~256 reg/wave cliff (+23MB symmetric FETCH/WRITE, attn 109.6->128.6us).
// attn here is BYTE-FOR-BYTE the r19/round-10 version (109.6us measured,
// FETCH 36.5/WRITE 47.7, no spill): per-tile l reduce with 2 in-loop shfls.
// qkv kept from r21 (dual-scratch epilogues, 2 row-sets/wave; non-attn
// 92.7 -> 90.1us measured). NO new experiments this round.
// ATTN REGISTER CLIFF (triple-confirmed): do not perturb the attn inner
// loop - defer-max, l-partials, V-direct, no-SB each tipped it into scratch.
// Carried: Q/K 3-product split-bf16 (r15: 2-product flips near-tie argmax),
// V-phase 2-product (linear error ~0.009), swapped-operand QK, per-lane
// softmax, in-lane P cvt via Vf bijection, 1 barrier/tile counted DMA,
// 2 q-sets/wave, split-K=4 grid 512, 4-way merge, (256,2) never-cap.

typedef __bf16 bf16x8 __attribute__((ext_vector_type(8)));
typedef _Float16 f16x8 __attribute__((ext_vector_type(8)));
typedef _Float16 f16x4 __attribute__((ext_vector_type(4)));
typedef float floatx4 __attribute__((ext_vector_type(4)));

#define MFMA16B(a, b, c) __builtin_amdgcn_mfma_f32_16x16x32_bf16(a, b, c, 0, 0, 0)
#define MFMA16F(a, b, c) __builtin_amdgcn_mfma_f32_16x16x32_f16(a, b, c, 0, 0, 0)
#define GLOAD_LDS16(g, l)                                                  \
  __builtin_amdgcn_global_load_lds(                                        \
      (const __attribute__((address_space(1))) void *)(g),                 \
      (__attribute__((address_space(3))) void *)(l), 16, 0, 0)

#define HID 256
#define LSEQ 4096
#define NB 4
#define NTOK (NB * LSEQ)             // 16384
#define PLANE ((size_t)NTOK * HID)   // 4,194,304 elements
#define NSPLIT 4                     // split-K over key range
#define QSCALE 0.09016844005556021f  // log2(e)/16 ; softmax uses exp2

// Layouts:
//  Wht/Wlt [3][n][h] row-major hi/lo bf16 weights (transposed).
//  Qf [tok][h] row-major fp16 (pre-scaled by QSCALE).
//  Kf (32-key tiles, T = tok>>5, 512 tiles): [T][nt(2)][kc(8)][lane(64)][j(8)]
//    fp16, tile stride 8192 el (16 KB).
//    element = K[key = T*32 + nt*16 + (lane&15)][h = kc*32 + (lane>>4)*8 + j]
//  Vf (32-key tiles): [T][dt(16)][lane][j] fp16, tile stride 8192 el.
//    element = V[key = T*32 + 4*(lane>>4) + (j&3) + 16*(j>>2)][d = dt*16 + (lane&15)]
//    (key<->k-slot bijection matches the swapped-QK per-lane key set).

__device__ __forceinline__ void split_bf16(float v, __bf16 &h, __bf16 &l) {
  h = (__bf16)v;
  l = (__bf16)(v - (float)h);
}

// ---------------------------------------------------------------------------
// Kernel 1: transpose + hi/lo-split weights -> Wht/Wlt [3][n][h] row-major.
// ---------------------------------------------------------------------------
__global__ __launch_bounds__(256) void wsplit(const float *__restrict__ Wq,
                                              const float *__restrict__ Wk,
                                              const float *__restrict__ Wv,
                                              __bf16 *__restrict__ Wht,
                                              __bf16 *__restrict__ Wlt) {
  __shared__ float tile[32][256];
  const int wsel = blockIdx.x;
  const int hb = blockIdx.y;
  const float *W = (wsel == 0) ? Wq : (wsel == 1) ? Wk : Wv;
  __bf16 *oh = Wht + wsel * HID * HID;
  __bf16 *ol = Wlt + wsel * HID * HID;
  const int t = threadIdx.x;
  #pragma unroll
  for (int p = 0; p < 8; ++p) {
    int r = p * 4 + (t >> 6);
    int c = (t & 63) * 4;
    *(floatx4 *)&tile[r][c] = *(const floatx4 *)&W[(hb * 32 + r) * HID + c];
  }
  __syncthreads();
  #pragma unroll
  for (int q = 0; q < 4; ++q) {
    int n = q * 64 + (t >> 2);
    int hs = (t & 3) * 8;
    bf16x8 hh, ll;
    #pragma unroll
    for (int i = 0; i < 8; ++i) {
      float v = tile[hs + i][n];
      __bf16 h, l;
      split_bf16(v, h, l);
      hh[i] = h; ll[i] = l;
    }
    *(bf16x8 *)&oh[n * HID + hb * 32 + hs] = hh;
    *(bf16x8 *)&ol[n * HID + hb * 32 + hs] = ll;
  }
}

// ---------------------------------------------------------------------------
// Kernel 2: QKV projection, 2 row-sets/wave (128-row m-tiles, grid (128,4) =
// 512 blocks = one residency round). Q/K: 3-product split-bf16; V: 2-product.
// Every W ds_read feeds 2 MFMAs. W temps load at phase top (short live range).
// K/V epilogues use dual scratch (Tf dedicated + Tf2 aliasing the dead WlS):
// both halves written, barriers 4->2 (K) and 4->1 (V), halves overlapped.
// (Measured passing in r21; non-attn 92.7 -> 90.1 us.)
// ---------------------------------------------------------------------------
__global__ __launch_bounds__(256, 2) void qkv_proj(const float *__restrict__ X,
                                                   const __bf16 *__restrict__ Wht,
                                                   const __bf16 *__restrict__ Wlt,
                                                   _Float16 *__restrict__ Qf,
                                                   _Float16 *__restrict__ Kf,
                                                   _Float16 *__restrict__ Vf) {
  __shared__ __bf16 WhS[64 * 256];
  __shared__ __bf16 WlS[64 * 256];
  __shared__ _Float16 Tf[64 * 72];   // dedicated transpose scratch (half 0)

  const int mtile = blockIdx.x;      // 128-row m-tile
  const int col0 = blockIdx.y * 64;
  const int tid = threadIdx.x;
  const int w4 = tid >> 6;
  const int lane = tid & 63;
  const int quad = lane >> 4;
  const int ln = lane & 15;
  const int arow0 = mtile * 128 + w4 * 16 + ln;
  const int arow1 = arow0 + 64;

  bf16x8 ah0[8], al0[8], ah1[8], al1[8];
  #pragma unroll
  for (int kc = 0; kc < 8; ++kc) {
    {
      const float *xp = X + (size_t)arow0 * HID + kc * 32 + quad * 8;
      floatx4 x0 = *(const floatx4 *)xp;
      floatx4 x1 = *(const floatx4 *)(xp + 4);
      #pragma unroll
      for (int j = 0; j < 4; ++j) {
        __bf16 h, l;
        split_bf16(x0[j], h, l); ah0[kc][j] = h; al0[kc][j] = l;
        split_bf16(x1[j], h, l); ah0[kc][4 + j] = h; al0[kc][4 + j] = l;
      }
    }
    {
      const float *xp = X + (size_t)arow1 * HID + kc * 32 + quad * 8;
      floatx4 x0 = *(const floatx4 *)xp;
      floatx4 x1 = *(const floatx4 *)(xp + 4);
      #pragma unroll
      for (int j = 0; j < 4; ++j) {
        __bf16 h, l;
        split_bf16(x0[j], h, l); ah1[kc][j] = h; al1[kc][j] = l;
        split_bf16(x1[j], h, l); ah1[kc][4 + j] = h; al1[kc][4 + j] = l;
      }
    }
  }

  const int srow = tid >> 2;
  const int sseg = tid & 3;

  for (int w = 0; w < 3; ++w) {
    // W(w) slab into temps; live range ends at the staging write below.
    bf16x8 th[8], tl[8];
    {
      const size_t wbase = (size_t)w * HID * HID + (size_t)(col0 + srow) * HID;
      #pragma unroll
      for (int j = 0; j < 8; ++j) {
        const int chunk = j * 4 + sseg;
        th[j] = *(const bf16x8 *)&Wht[wbase + chunk * 8];
        if (w < 2) tl[j] = *(const bf16x8 *)&Wlt[wbase + chunk * 8];
      }
    }
    __syncthreads();  // prev phase's LDS consumers (MFMA / Tf2 reads) done
    #pragma unroll
    for (int j = 0; j < 8; ++j) {
      const int chunk = j * 4 + sseg;
      const int dst = srow * 256 + ((chunk ^ (srow & 7)) << 3);
      *(bf16x8 *)&WhS[dst] = th[j];
      if (w < 2) *(bf16x8 *)&WlS[dst] = tl[j];  // V phase reads hi only
    }
    __syncthreads();

    floatx4 acc0[4] = {}, acc1[4] = {};
    #pragma unroll
    for (int kc = 0; kc < 8; ++kc) {
      #pragma unroll
      for (int nt = 0; nt < 4; ++nt) {
        const int a = (nt * 16 + ln) * 256 + (((kc * 4 + quad) ^ (ln & 7)) << 3);
        bf16x8 bh = *(const bf16x8 *)&WhS[a];
        acc0[nt] = MFMA16B(ah0[kc], bh, acc0[nt]);
        acc1[nt] = MFMA16B(ah1[kc], bh, acc1[nt]);
        if (w < 2) {
          bf16x8 bl = *(const bf16x8 *)&WlS[a];
          acc0[nt] = MFMA16B(ah0[kc], bl, acc0[nt]);
          acc1[nt] = MFMA16B(ah1[kc], bl, acc1[nt]);
        }
        acc0[nt] = MFMA16B(al0[kc], bh, acc0[nt]);
        acc1[nt] = MFMA16B(al1[kc], bh, acc1[nt]);
      }
    }

    // Epilogues. C/D layout: col = lane&15, row = quad*4 + reg.
    if (w == 0) {
      #pragma unroll
      for (int nt = 0; nt < 4; ++nt) {
        #pragma unroll
        for (int r = 0; r < 4; ++r) {
          const int orow = mtile * 128 + w4 * 16 + quad * 4 + r;
          const int ocol = col0 + nt * 16 + ln;
          Qf[(size_t)orow * HID + ocol] = (_Float16)(acc0[nt][r] * QSCALE);
          Qf[(size_t)(orow + 64) * HID + ocol] = (_Float16)(acc1[nt][r] * QSCALE);
        }
      }
    } else if (w == 1) {
      _Float16 *Tf2 = (_Float16 *)WlS;  // WlS dead after this phase's MFMAs
      // half 0 -> Tf (dedicated; no hazard, write immediately)
      #pragma unroll
      for (int nt = 0; nt < 4; ++nt)
        #pragma unroll
        for (int r = 0; r < 4; ++r) {
          const int tok_l = w4 * 16 + quad * 4 + r;
          const int h_l = nt * 16 + ln;
          Tf[tok_l * 72 + h_l] = (_Float16)acc0[nt][r];
        }
      __syncthreads();  // all waves' MFMA reads of WhS/WlS done; Tf visible
      // half 1 -> Tf2 (aliases WlS, now free); overlaps half-0 shuffle reads
      #pragma unroll
      for (int nt = 0; nt < 4; ++nt)
        #pragma unroll
        for (int r = 0; r < 4; ++r) {
          const int tok_l = w4 * 16 + quad * 4 + r;
          const int h_l = nt * 16 + ln;
          Tf2[tok_l * 72 + h_l] = (_Float16)acc1[nt][r];
        }
      #pragma unroll
      for (int i = 0; i < 2; ++i) {     // half 0: 512 chunks of 16B
        const int c = i * 256 + tid;
        const int lane_f = c & 63;
        const int ntf = (c >> 6) & 1;
        const int kcL = (c >> 7) & 1;
        const int t2 = (c >> 8) & 1;
        const int qf = lane_f >> 4;
        const int lnf = lane_f & 15;
        const int tok_l = t2 * 32 + ntf * 16 + lnf;
        f16x8 v = *(const f16x8 *)&Tf[tok_l * 72 + kcL * 32 + qf * 8];
        const int T = mtile * 4 + t2;
        const int kc2 = (col0 >> 5) + kcL;
        *(f16x8 *)&Kf[(size_t)T * 8192 + ((ntf * 8 + kc2) * 64 + lane_f) * 8] = v;
      }
      __syncthreads();  // Tf2 visible
      #pragma unroll
      for (int i = 0; i < 2; ++i) {     // half 1
        const int c = i * 256 + tid;
        const int lane_f = c & 63;
        const int ntf = (c >> 6) & 1;
        const int kcL = (c >> 7) & 1;
        const int t2 = (c >> 8) & 1;
        const int qf = lane_f >> 4;
        const int lnf = lane_f & 15;
        const int tok_l = t2 * 32 + ntf * 16 + lnf;
        f16x8 v = *(const f16x8 *)&Tf2[tok_l * 72 + kcL * 32 + qf * 8];
        const int T = mtile * 4 + 2 + t2;
        const int kc2 = (col0 >> 5) + kcL;
        *(f16x8 *)&Kf[(size_t)T * 8192 + ((ntf * 8 + kc2) * 64 + lane_f) * 8] = v;
      }
      // w==2's phase-top barrier covers Tf2 reads before any WhS restage.
    } else {
      _Float16 *Tf2 = (_Float16 *)WlS;  // WlS entirely unused in the V phase
      #pragma unroll
      for (int nt = 0; nt < 4; ++nt)
        #pragma unroll
        for (int r = 0; r < 4; ++r) {
          const int tok_l = w4 * 16 + quad * 4 + r;
          const int d_l = nt * 16 + ln;
          Tf[d_l * 72 + tok_l] = (_Float16)acc0[nt][r];
          Tf2[d_l * 72 + tok_l] = (_Float16)acc1[nt][r];
        }
      __syncthreads();
      #pragma unroll
      for (int i = 0; i < 2; ++i) {     // half 0
        const int c = i * 256 + tid;
        const int lane_f = c & 63;
        const int dtL = (c >> 6) & 3;
        const int t2 = (c >> 8) & 1;
        const int qf = lane_f >> 4;
        const int lnf = lane_f & 15;
        const int d_l = dtL * 16 + lnf;
        // Bijection: v[j] = V_local[key = t2*32 + 4*qf + (j&3) + 16*(j>>2)][d_l]
        f16x4 lo = *(const f16x4 *)&Tf[d_l * 72 + t2 * 32 + 4 * qf];
        f16x4 hi = *(const f16x4 *)&Tf[d_l * 72 + t2 * 32 + 16 + 4 * qf];
        f16x8 v;
        v[0] = lo[0]; v[1] = lo[1]; v[2] = lo[2]; v[3] = lo[3];
        v[4] = hi[0]; v[5] = hi[1]; v[6] = hi[2]; v[7] = hi[3];
        const int T = mtile * 4 + t2;
        const int dt = (col0 >> 4) + dtL;
        *(f16x8 *)&Vf[(size_t)(T * 16 + dt) * 512 + lane_f * 8] = v;
      }
      #pragma unroll
      for (int i = 0; i < 2; ++i) {     // half 1
        const int c = i * 256 + tid;
        const int lane_f = c & 63;
        const int dtL = (c >> 6) & 3;
        const int t2 = (c >> 8) & 1;
        const int qf = lane_f >> 4;
        const int lnf = lane_f & 15;
        const int d_l = dtL * 16 + lnf;
        f16x4 lo = *(const f16x4 *)&Tf2[d_l * 72 + t2 * 32 + 4 * qf];
        f16x4 hi = *(const f16x4 *)&Tf2[d_l * 72 + t2 * 32 + 16 + 4 * qf];
        f16x8 v;
        v[0] = lo[0]; v[1] = lo[1]; v[2] = lo[2]; v[3] = lo[3];
        v[4] = hi[0]; v[5] = hi[1]; v[6] = hi[2]; v[7] = hi[3];
        const int T = mtile * 4 + 2 + t2;
        const int dt = (col0 >> 4) + dtL;
        *(f16x8 *)&Vf[(size_t)(T * 16 + dt) * 512 + lane_f * 8] = v;
      }
    }
  }
}

// ---------------------------------------------------------------------------
// Kernel 3: flash attention, swapped-operand core, 2 q-sets/wave.
// EXACT r19/round-10 configuration (measured 109.6 us, FETCH 36.5/WRITE 47.7,
// no spill). Per-tile l reduce with 2 in-loop shfls. DO NOT PERTURB (register
// cliff at ~256/wave: l-partials, defer-max, V-direct, no-SB all spilled).
// grid = 512 (qt=bx>>2 over 128-token q-blocks, ks=bx&3), 256 thr,
// LDS 64 KB (K/V dbuf), 2 blocks/CU.
// ---------------------------------------------------------------------------
__global__ __launch_bounds__(256, 2) void attn(const _Float16 *__restrict__ Qf,
                                               const _Float16 *__restrict__ Kf,
                                               const _Float16 *__restrict__ Vf,
                                               _Float16 *__restrict__ Op,
                                               float *__restrict__ Mp,
                                               float *__restrict__ Lp) {
  __shared__ _Float16 KS[2][8192];
  __shared__ _Float16 VS[2][8192];

  const int bx = blockIdx.x;
  const int ks = bx & 3;
  const int qt = bx >> 2;            // 0..127: 128-token q-block
  const int b = qt >> 5;             // 32 q-blocks per batch
  const int qtl = qt & 31;
  const int tid = threadIdx.x;
  const int w4 = tid >> 6;
  const int lane = tid & 63;
  const int quad = lane >> 4;
  const int ln = lane & 15;
  const int T0 = b * 128 + ks * 32;  // 32 key-tiles (1024 keys) per block

  // This lane's two q tokens (q = lane&15 in the swapped layout).
  const int qtok0 = b * LSEQ + qtl * 128 + w4 * 16 + ln;
  const int qtok1 = qtok0 + 64;
  f16x8 q0[8], q1[8];
  #pragma unroll
  for (int kc = 0; kc < 8; ++kc) {
    q0[kc] = *(const f16x8 *)&Qf[(size_t)qtok0 * HID + kc * 32 + quad * 8];
    q1[kc] = *(const f16x8 *)&Qf[(size_t)qtok1 * HID + kc * 32 + quad * 8];
  }

  const _Float16 *kuni = Kf + (size_t)T0 * 8192;
  const _Float16 *vuni = Vf + (size_t)T0 * 8192;
  const int koff = tid * 8;
  const int voff = lane * 8;

  // Prologue: DMA tile 0 -> buffers 0.
  #pragma unroll
  for (int i = 0; i < 4; ++i)
    GLOAD_LDS16(kuni + i * 2048 + koff, &KS[0][i * 2048 + koff]);
  #pragma unroll
  for (int i = 0; i < 4; ++i)
    GLOAD_LDS16(vuni + i * 2048 + koff, &VS[0][i * 2048 + koff]);

  float m0 = -1e30f, m1 = -1e30f;
  float l0 = 0.f, l1 = 0.f;
  floatx4 o0[16] = {}, o1[16] = {};

  for (int t = 0; t < 32; ++t) {
    const int buf = t & 1;
    // Own tile-t DMA done (issued one full tile ago); queue empty otherwise.
    asm volatile("s_waitcnt vmcnt(0)" ::: "memory");
    __builtin_amdgcn_s_barrier();  // all waves' quarters in LDS; prev bufs free
    __builtin_amdgcn_sched_barrier(0);
    if (t < 31) {
      const _Float16 *ksrc = kuni + (size_t)(t + 1) * 8192 + koff;
      const _Float16 *vsrc = vuni + (size_t)(t + 1) * 8192 + koff;
      #pragma unroll
      for (int i = 0; i < 4; ++i)
        GLOAD_LDS16(ksrc + i * 2048, &KS[buf ^ 1][i * 2048 + koff]);
      #pragma unroll
      for (int i = 0; i < 4; ++i)
        GLOAD_LDS16(vsrc + i * 2048, &VS[buf ^ 1][i * 2048 + koff]);
    }
    const _Float16 *Kb = KS[buf];
    const _Float16 *Vb = VS[buf];

    // ---------- QK^T swapped: S^T = mfma(K, Q); each K-frag feeds 2 MFMAs --
    floatx4 s00, s01, s10, s11;  // s{qset}{nt}
    {
      floatx4 a00 = {}, b00 = {}, a01 = {}, b01 = {};
      floatx4 a10 = {}, b10 = {}, a11 = {}, b11 = {};
      __builtin_amdgcn_s_setprio(1);
      #pragma unroll
      for (int kc = 0; kc < 4; ++kc) {
        const f16x8 k0 = *(const f16x8 *)(Kb + kc * 512 + voff);
        const f16x8 k1 = *(const f16x8 *)(Kb + (4 + kc) * 512 + voff);
        const f16x8 k2 = *(const f16x8 *)(Kb + (8 + kc) * 512 + voff);
        const f16x8 k3 = *(const f16x8 *)(Kb + (12 + kc) * 512 + voff);
        a00 = MFMA16F(k0, q0[kc], a00);
        a10 = MFMA16F(k0, q1[kc], a10);
        b00 = MFMA16F(k1, q0[4 + kc], b00);
        b10 = MFMA16F(k1, q1[4 + kc], b10);
        a01 = MFMA16F(k2, q0[kc], a01);
        a11 = MFMA16F(k2, q1[kc], a11);
        b01 = MFMA16F(k3, q0[4 + kc], b01);
        b11 = MFMA16F(k3, q1[4 + kc], b11);
      }
      __builtin_amdgcn_s_setprio(0);
      s00 = a00 + b00; s01 = a01 + b01;
      s10 = a10 + b10; s11 = a11 + b11;
    }

    // ---------- per-lane softmax over 32 keys, q-set 0 (q = ln) ----------
    float al0, al1;
    {
      float tmax = fmaxf(fmaxf(fmaxf(s00[0], s00[1]), fmaxf(s00[2], s00[3])),
                         fmaxf(fmaxf(s01[0], s01[1]), fmaxf(s01[2], s01[3])));
      tmax = fmaxf(tmax, __shfl_xor(tmax, 16));
      tmax = fmaxf(tmax, __shfl_xor(tmax, 32));
      const float mn = fmaxf(m0, tmax);
      al0 = exp2f(m0 - mn);
      #pragma unroll
      for (int i = 0; i < 4; ++i) {
        s00[i] = exp2f(s00[i] - mn);
        s01[i] = exp2f(s01[i] - mn);
      }
      float rs = ((s00[0] + s00[1]) + (s00[2] + s00[3])) +
                 ((s01[0] + s01[1]) + (s01[2] + s01[3]));
      rs += __shfl_xor(rs, 16);
      rs += __shfl_xor(rs, 32);
      l0 = l0 * al0 + rs;
      m0 = mn;
    }
    // ---------- q-set 1 ----------
    {
      float tmax = fmaxf(fmaxf(fmaxf(s10[0], s10[1]), fmaxf(s10[2], s10[3])),
                         fmaxf(fmaxf(s11[0], s11[1]), fmaxf(s11[2], s11[3])));
      tmax = fmaxf(tmax, __shfl_xor(tmax, 16));
      tmax = fmaxf(tmax, __shfl_xor(tmax, 32));
      const float mn = fmaxf(m1, tmax);
      al1 = exp2f(m1 - mn);
      #pragma unroll
      for (int i = 0; i < 4; ++i) {
        s10[i] = exp2f(s10[i] - mn);
        s11[i] = exp2f(s11[i] - mn);
      }
      float rs = ((s10[0] + s10[1]) + (s10[2] + s10[3])) +
                 ((s11[0] + s11[1]) + (s11[2] + s11[3]));
      rs += __shfl_xor(rs, 16);
      rs += __shfl_xor(rs, 32);
      l1 = l1 * al1 + rs;
      m1 = mn;
    }

    // ---------- P fragments: pure in-lane cvt ----------
    f16x8 pf0, pf1;
    pf0[0] = (_Float16)s00[0]; pf0[1] = (_Float16)s00[1];
    pf0[2] = (_Float16)s00[2]; pf0[3] = (_Float16)s00[3];
    pf0[4] = (_Float16)s01[0]; pf0[5] = (_Float16)s01[1];
    pf0[6] = (_Float16)s01[2]; pf0[7] = (_Float16)s01[3];
    pf1[0] = (_Float16)s10[0]; pf1[1] = (_Float16)s10[1];
    pf1[2] = (_Float16)s10[2]; pf1[3] = (_Float16)s10[3];
    pf1[4] = (_Float16)s11[0]; pf1[5] = (_Float16)s11[1];
    pf1[6] = (_Float16)s11[2]; pf1[7] = (_Float16)s11[3];

    // ---------- O rescale (alpha-skip, per q-set) ----------
    if (__any(al0 < 1.0f)) {
      #pragma unroll
      for (int dt = 0; dt < 16; ++dt) {
        o0[dt][0] *= al0; o0[dt][1] *= al0; o0[dt][2] *= al0; o0[dt][3] *= al0;
      }
    }
    if (__any(al1 < 1.0f)) {
      #pragma unroll
      for (int dt = 0; dt < 16; ++dt) {
        o1[dt][0] *= al1; o1[dt][1] *= al1; o1[dt][2] *= al1; o1[dt][3] *= al1;
      }
    }

    // ---------- O^T += V^T P ; each V-frag feeds 2 MFMAs ----------
    __builtin_amdgcn_s_setprio(1);
    #pragma unroll
    for (int dt = 0; dt < 16; ++dt) {
      const f16x8 vf = *(const f16x8 *)(Vb + dt * 512 + voff);
      o0[dt] = MFMA16F(vf, pf0, o0[dt]);
      o1[dt] = MFMA16F(vf, pf1, o1[dt]);
    }
    __builtin_amdgcn_s_setprio(0);
    __builtin_amdgcn_sched_barrier(0);
  }

  // Epilogue: lane owns q = qtok0/qtok1; d = dt*16 + quad*4 + r.
  #pragma unroll
  for (int dt = 0; dt < 16; ++dt) {
    f16x4 v4;
    v4[0] = (_Float16)o0[dt][0]; v4[1] = (_Float16)o0[dt][1];
    v4[2] = (_Float16)o0[dt][2]; v4[3] = (_Float16)o0[dt][3];
    *(f16x4 *)&Op[(size_t)ks * PLANE + (size_t)qtok0 * HID + dt * 16 + quad * 4] = v4;
    f16x4 w4v;
    w4v[0] = (_Float16)o1[dt][0]; w4v[1] = (_Float16)o1[dt][1];
    w4v[2] = (_Float16)o1[dt][2]; w4v[3] = (_Float16)o1[dt][3];
    *(f16x4 *)&Op[(size_t)ks * PLANE + (size_t)qtok1 * HID + dt * 16 + quad * 4] = w4v;
  }
  if (quad == 0) {
    Mp[ks * NTOK + qtok0] = m0;
    Lp[ks * NTOK + qtok0] = l0;
    Mp[ks * NTOK + qtok1] = m1;
    Lp[ks * NTOK + qtok1] = l1;
  }
}

// ---------------------------------------------------------------------------
// Kernel 4: split-K merge, 4-way (fp16 partials).
// ---------------------------------------------------------------------------
__global__ __launch_bounds__(256) void merge(const _Float16 *__restrict__ Op,
                                             const float *__restrict__ Mp,
                                             const float *__restrict__ Lp,
                                             float *__restrict__ Out) {
  const int row = blockIdx.x * 4 + (threadIdx.x >> 6);
  const int c = (threadIdx.x & 63) * 4;
  float ms[NSPLIT], ls[NSPLIT];
  #pragma unroll
  for (int s = 0; s < NSPLIT; ++s) {
    ms[s] = Mp[s * NTOK + row];
    ls[s] = Lp[s * NTOK + row];
  }
  const float M = fmaxf(fmaxf(ms[0], ms[1]), fmaxf(ms[2], ms[3]));
  float e[NSPLIT], den = 0.f;
  #pragma unroll
  for (int s = 0; s < NSPLIT; ++s) {
    e[s] = exp2f(ms[s] - M);
    den += ls[s] * e[s];
  }
  const float inv = 1.0f / den;
  floatx4 out = {};
  #pragma unroll
  for (int s = 0; s < NSPLIT; ++s) {
    const f16x4 a = *(const f16x4 *)&Op[(size_t)s * PLANE + (size_t)row * HID + c];
    const float w = e[s] * inv;
    #pragma unroll
    for (int i = 0; i < 4; ++i) out[i] += w * (float)a[i];
  }
  *(floatx4 *)&Out[(size_t)row * HID + c] = out;
}

// ---------------------------------------------------------------------------
extern "C" void kernel_launch(void *const *d_in, const int *in_sizes, int n_in,
                              void *d_out, int out_size, void *d_ws, size_t ws_size,
                              hipStream_t stream) {
  const float *X = (const float *)d_in[0];
  const float *Wq = (const float *)d_in[1];
  const float *Wk = (const float *)d_in[2];
  const float *Wv = (const float *)d_in[3];
  // d_in[4] = lengths (unused by reference)

  // Workspace (2-byte elements). ~60 MB total.
  _Float16 *ws = (_Float16 *)d_ws;
  _Float16 *Qf = ws;                          // [16384][256] row-major fp16
  _Float16 *Kf = Qf + PLANE;                  // 32-key frag-linear fp16
  _Float16 *Vf = Kf + PLANE;                  // 32-key frag-linear fp16
  __bf16 *Wht = (__bf16 *)(Vf + PLANE);       // [3][256][256] bf16 hi
  __bf16 *Wlt = Wht + 3 * HID * HID;          // bf16 lo
  _Float16 *Op = (_Float16 *)(Wlt + 3 * HID * HID);  // [4][16384][256] fp16
  float *Mp = (float *)(Op + NSPLIT * PLANE); // [4][16384]
  float *Lp = Mp + NSPLIT * NTOK;             // [4][16384]

  wsplit<<<dim3(3, 8), 256, 0, stream>>>(Wq, Wk, Wv, Wht, Wlt);
  qkv_proj<<<dim3(128, 4), 256, 0, stream>>>(X, Wht, Wlt, Qf, Kf, Vf);
  attn<<<NTOK / 128 * NSPLIT, 256, 0, stream>>>(Qf, Kf, Vf, Op, Mp, Lp);
  merge<<<NTOK / 4, 256, 0, stream>>>(Op, Mp, Lp, (float *)d_out);
}